// Round 17
// baseline (200.316 us; speedup 1.0000x reference)
//
#include <hip/hip_runtime.h>
#include <hip/hip_bf16.h>
#include <stdint.h>

typedef __hip_bfloat16 bf16;
typedef __attribute__((ext_vector_type(8))) short bf16x8;  // MFMA A/B frag (4 VGPRs)
typedef __attribute__((ext_vector_type(4))) float f32x4;   // MFMA C/D frag

__device__ __forceinline__ bf16x8 ldsv8(const bf16* p) { return *(const bf16x8*)p; }

__device__ __forceinline__ short bf_bits(float f) {
  union { bf16 h; short s; } u; u.h = __float2bfloat16(f); return u.s;
}

// Q pre-scale: 1/sqrt(64) * log2(e), so attn can use exp2 (v_exp_f32) directly.
#define QSCALE 0.18033688011112042f

// async global->LDS, 16 B/lane. LDS dst must be wave-uniform base + lane*16,
// which our slot layout satisfies (slot = i*256 + wave*64 + lane).
#define ASYNC16(ldsdst, gsrc)                                                  \
  __builtin_amdgcn_global_load_lds(                                            \
      (const __attribute__((address_space(1))) void*)(gsrc),                   \
      (__attribute__((address_space(3))) void*)(ldsdst), 16, 0, 0)

// Runtime dtype sniff: true if buffer holds bf16 (vs fp32).
__device__ __forceinline__ bool is_bf16(const void* p) {
  const uint32_t* w = (const uint32_t*)p;
  int cnt = 0;
#pragma unroll 8
  for (int i = 0; i < 64; ++i) {
    uint32_t e = (w[i] >> 7) & 0xffu;
    cnt += (e >= 100u && e <= 150u) ? 1 : 0;
  }
  return cnt >= 40;
}

__device__ __forceinline__ float load_f32(const void* p, size_t idx, bool b16) {
  return b16 ? __bfloat162float(((const bf16*)p)[idx]) : ((const float*)p)[idx];
}

// ---------------- shared transpose-convert body ----------------
__device__ __forceinline__ void cvtT_body(const void* in, bf16* out, int R,
                                          int Ccols, int bx, int by,
                                          bf16 (*tile)[33]) {
  const bool b16 = is_bf16(in);
  int tx = threadIdx.x & 31, ty = threadIdx.x >> 5;
  int c0 = bx * 32, r0 = by * 32;
#pragma unroll
  for (int i = 0; i < 32; i += 8)
    tile[ty + i][tx] = __float2bfloat16(load_f32(in, (size_t)(r0 + ty + i) * Ccols + c0 + tx, b16));
  __syncthreads();
#pragma unroll
  for (int i = 0; i < 32; i += 8)
    out[(size_t)(c0 + ty + i) * R + r0 + tx] = tile[tx][ty + i];
}

// ---------------- fused prep: x cvt + WqkvT + WprojT in ONE launch ----------
// blocks [0,2048): x fp32->bf16; [2048,5120): Wqkv cvtT; [5120,6144): Wproj cvtT.
// Branch is uniform per block, so cvtT_body's __syncthreads is safe.
__global__ __launch_bounds__(256) void prep_k(const float* __restrict__ x,
                                              bf16* __restrict__ xb,
                                              const void* __restrict__ Wqkv,
                                              bf16* __restrict__ WqkvT,
                                              const void* __restrict__ Wproj,
                                              bf16* __restrict__ WprojT) {
  __shared__ __align__(16) bf16 tile[32][33];
  const int id = blockIdx.x;
  if (id < 2048) {
    size_t i = (size_t)id * 256 + threadIdx.x;
    const float4 f0 = ((const float4*)x)[i * 2];
    const float4 f1 = ((const float4*)x)[i * 2 + 1];
    bf16x8 pk = {bf_bits(f0.x), bf_bits(f0.y), bf_bits(f0.z), bf_bits(f0.w),
                 bf_bits(f1.x), bf_bits(f1.y), bf_bits(f1.z), bf_bits(f1.w)};
    ((bf16x8*)xb)[i] = pk;
  } else if (id < 5120) {
    int id2 = id - 2048;
    cvtT_body(Wqkv, WqkvT, 1024, 3072, id2 % 96, id2 / 96, tile);
  } else {
    int id3 = id - 5120;
    cvtT_body(Wproj, WprojT, 1024, 1024, id3 % 32, id3 / 32, tile);
  }
}

// standalone cvtT (fallback paths)
__global__ __launch_bounds__(256) void cvtT_k(const void* __restrict__ in,
                                              bf16* __restrict__ out,
                                              int R, int Ccols) {
  __shared__ __align__(16) bf16 tile[32][33];
  cvtT_body(in, out, R, Ccols, blockIdx.x, blockIdx.y, tile);
}

// standalone cvt (fallback path)
__global__ __launch_bounds__(256) void cvt_k(const float* __restrict__ in,
                                             bf16* __restrict__ out) {
  size_t i = (size_t)blockIdx.x * 256 + threadIdx.x;
  const float4 f0 = ((const float4*)in)[i * 2];
  const float4 f1 = ((const float4*)in)[i * 2 + 1];
  bf16x8 pk = {bf_bits(f0.x), bf_bits(f0.y), bf_bits(f0.z), bf_bits(f0.w),
               bf_bits(f1.x), bf_bits(f1.y), bf_bits(f1.z), bf_bits(f1.w)};
  ((bf16x8*)out)[i] = pk;
}

// ---------------- 128xBN MFMA GEMM, A[M,1024] x BT[N,1024] ----------------
// m97-style global_load_lds staging (width 16). MODE 0: out = bf16 xproj
// [M][3072], Q cols x QSCALE. MODE 1: out = FLOAT32 [M][1024].
// T1 XCD swizzle, A-RESIDENT orientation (R16 best): m = swz/gridDim.y.
template <int MODE, int BN>
__global__ __launch_bounds__(256) void gemm128(
    const void* __restrict__ Araw, const bf16* __restrict__ BT,
    const void* __restrict__ biasraw, void* __restrict__ outv) {
  constexpr int K = 1024;
  constexpr int NBF = BN / 32;  // B frags per wave (wave n-extent BN/2)
  __shared__ __align__(16) bf16 As[128 * 32];
  __shared__ __align__(16) bf16 Bs[BN * 32];
  const int tid = threadIdx.x;
  const int wave = tid >> 6, lane = tid & 63;
  const int quad = lane >> 4, l16 = lane & 15;
  const int nwg = gridDim.x * gridDim.y;
  const int lin = blockIdx.y * gridDim.x + blockIdx.x;
  const int swz = (lin & 7) * (nwg >> 3) + (lin >> 3);
  const int m0 = (swz / gridDim.y) * 128, n0 = (swz % gridDim.y) * BN;
  const int wm = (wave & 1) * 64, wn = (wave >> 1) * (BN / 2);
  const bool a16 = (MODE == 0) ? is_bf16(Araw) : true;
  const bool bias16 = is_bf16(biasraw);

  f32x4 acc[4][NBF] = {};

  for (int kt = 0; kt < K; kt += 32) {
    __syncthreads();
    if (MODE != 0 || a16) {
#pragma unroll
      for (int i = 0; i < 2; ++i) {  // A: 512 slots
        int slot = i * 256 + tid;
        int row = slot >> 2, col = (slot & 3) << 3;
        ASYNC16(As + slot * 8, ((const bf16*)Araw) + (size_t)(m0 + row) * K + kt + col);
      }
#pragma unroll
      for (int i = 0; i < BN / 64; ++i) {  // B: BN*4 slots
        int slot = i * 256 + tid;
        int row = slot >> 2, col = (slot & 3) << 3;
        ASYNC16(Bs + slot * 8, BT + (size_t)(n0 + row) * K + kt + col);
      }
    } else {  // fp32 A fallback: convert through registers
#pragma unroll
      for (int i = 0; i < 2; ++i) {
        int slot = i * 256 + tid;
        int row = slot >> 2, col = (slot & 3) << 3;
        const float* ap = ((const float*)Araw) + (size_t)(m0 + row) * K + kt + col;
        float4 f0 = *(const float4*)ap;
        float4 f1 = *(const float4*)(ap + 4);
        bf16x8 pk = {bf_bits(f0.x), bf_bits(f0.y), bf_bits(f0.z), bf_bits(f0.w),
                     bf_bits(f1.x), bf_bits(f1.y), bf_bits(f1.z), bf_bits(f1.w)};
        *(bf16x8*)(As + slot * 8) = pk;
        if (i * 256 < BN * 4)
          *(bf16x8*)(Bs + slot * 8) = *(const bf16x8*)(BT + (size_t)(n0 + row) * K + kt + col);
      }
    }
    __syncthreads();
    bf16x8 af[4], bfr[NBF];
#pragma unroll
    for (int i = 0; i < 4; ++i)
      af[i] = ldsv8(As + (wm + i * 16 + l16) * 32 + quad * 8);
#pragma unroll
    for (int j = 0; j < NBF; ++j)
      bfr[j] = ldsv8(Bs + (wn + j * 16 + l16) * 32 + quad * 8);
#pragma unroll
    for (int i = 0; i < 4; ++i)
#pragma unroll
      for (int j = 0; j < NBF; ++j)
        acc[i][j] = __builtin_amdgcn_mfma_f32_16x16x32_bf16(af[i], bfr[j], acc[i][j], 0, 0, 0);
  }

  float biasf[NBF];
#pragma unroll
  for (int j = 0; j < NBF; ++j)
    biasf[j] = load_f32(biasraw, n0 + wn + j * 16 + l16, bias16);

#pragma unroll
  for (int i = 0; i < 4; ++i)
#pragma unroll
    for (int j = 0; j < NBF; ++j) {
      int ng = n0 + wn + j * 16 + l16;
#pragma unroll
      for (int r = 0; r < 4; ++r) {
        int mg = m0 + wm + i * 16 + quad * 4 + r;  // C/D: row=quad*4+reg, col=l16
        float v = acc[i][j][r] + biasf[j];
        if (MODE == 1) {
          ((float*)outv)[(size_t)mg * 1024 + ng] = v;  // final output fp32
        } else {
          ((bf16*)outv)[(size_t)mg * 3072 + ng] =
              __float2bfloat16(ng < 1024 ? v * QSCALE : v);
        }
      }
    }
}

// ---------------- MFMA flash causal attention, KEY-HALF balanced ------------
// R13/R16 structure (static softmax via exp2, denominator via all-ones MFMA,
// dbuf K/V LDS, single barrier/step, 1024 thr / 16 waves) + phase-2 key-half
// split for PERFECT balance without extra registers (R12's failure was dual
// staging streams -> spills; here staging stays single-stream phase-1-style):
//   phase 1 (st=0..pid): A-waves (0-7) full-tile steps on tile qtA=pid,
//     B-waves (8-15) on tile qtB=15-pid. A finishes exactly at st=pid
//     (diag), writes tile-A output, reloads Q for tile B, zeroes o/lacc.
//   phase 2 (st=pid+1..qtB): ALL waves on tile B; partner pair (w, w+8) owns
//     the same 16 q-rows; wave takes key half kh=tl of each staged tile
//     (chunks ks=2*kh,2*kh+1 of the existing P/V swizzle formulas; each wave's
//     private Pw -> no stale-half reads). Per-wave compute halves (sc[4]).
//   merge: A's tile-B partials summed into B via LDS scratch (static softmax
//     makes partials addable), B writes tile-B output.
// Block cost: (pid+1) full + (15-2pid) half steps ~= constant across pids
// (was 9..16 full). Register high-water = phase 1 = R13's (64 VGPR, no spill;
// WRITE_SIZE ~11 MB is the spill sentinel).
// Quirky reshape: head-row (h,s) of Q/K/V = 64 contiguous elems of xproj at
// row h*128+(s>>4), col (s&15)*64 (+1024 K, +2048 V). Q carries QSCALE.
// LDS 141.3 KB, 1 block/CU, 4 waves/SIMD. Swizzles:
//   V: element (d,s) at VT[d*136 + (s ^ ((d>>3)<<3))]
//   P: element (row,s) at Pw[row*136 + (s ^ ((row>>2)<<3))]
__global__ __launch_bounds__(1024, 4) void attn_k(const bf16* __restrict__ xproj,
                                                  bf16* __restrict__ Yb) {
  constexpr int KSZ = 128 * 72;   // elems per K buffer
  constexpr int VSZ = 64 * 136;   // elems per V buffer
  __shared__ __align__(16) bf16 Ks[2 * KSZ];        // [buf][s][d], stride 72
  __shared__ __align__(16) bf16 VTs[2 * VSZ];       // [buf][d][s^], swizzled
  __shared__ __align__(16) bf16 Ps[16 * 16 * 136];  // per-wave P round-trip

  const int tid = threadIdx.x;
  const int wave = tid >> 6, lane = tid & 63;
  const int quad = lane >> 4, l16 = lane & 15;
  const int tl = wave >> 3;                // phase1: 0=tile A, 1=tile B; phase2: key half
  const int wrow = (wave & 7) * 16;        // row block within the q-tile
  const int pid = blockIdx.x;              // 0..7
  const int qtA = pid, qtB = 15 - pid;
  const int bh = blockIdx.y, b = bh >> 4, h = bh & 15;
  const size_t rowbase = (size_t)(b * 2048 + h * 128) * 3072;

  const short onebits = (short)0x3F80;
  const bf16x8 vones = {onebits, onebits, onebits, onebits,
                        onebits, onebits, onebits, onebits};

  bf16x8 aq[2];  // Q frags (A-layout: m=l16, k=quad*8+j)
  {
    int sg = (tl ? qtB : qtA) * 128 + wrow + l16;
    const bf16* qp = xproj + rowbase + (size_t)(sg >> 4) * 3072 + ((sg & 15) << 6);
#pragma unroll
    for (int ks = 0; ks < 2; ++ks)
      aq[ks] = *(const bf16x8*)(qp + ks * 32 + quad * 8);
  }

  f32x4 o[4] = {};
  f32x4 lacc = {};

  bf16* Pw = Ps + wave * (16 * 136);
  bf16* Yh = Yb + (size_t)b * 2097152 + h * 64;  // Y[b][t][h*64+d]

  // per-thread staging slot: 1024 slots = 128 s-rows x 8 d-blocks
  const int sA = tid >> 3, blkA = tid & 7;

  bf16x8 kreg, vreg;
#define ISSUE_LOADS(stv)                                                        \
  {                                                                             \
    int sg0 = (stv)*128 + sA;                                                   \
    const bf16* b0 = xproj + rowbase + (size_t)(sg0 >> 4) * 3072 + ((sg0 & 15) << 6); \
    kreg = *(const bf16x8*)(b0 + 1024 + blkA * 8);                              \
    vreg = *(const bf16x8*)(b0 + 2048 + blkA * 8);                              \
  }
#define WRITE_TILE(buf)                                                         \
  {                                                                             \
    bf16* Kd = Ks + (buf)*KSZ;                                                  \
    bf16* Vd = VTs + (buf)*VSZ;                                                 \
    *(bf16x8*)(Kd + sA * 72 + blkA * 8) = kreg;                                 \
    const bf16* vv = (const bf16*)&vreg;                                        \
    const int ssw = sA ^ (blkA << 3);                                           \
    _Pragma("unroll")                                                           \
    for (int j = 0; j < 8; ++j) Vd[(blkA * 8 + j) * 136 + ssw] = vv[j];         \
  }

  // prologue: stage tile 0 into buf0, issue tile 1 (qtB >= 8 always)
  ISSUE_LOADS(0);
  WRITE_TILE(0);
  ISSUE_LOADS(1);
  __syncthreads();

  int cur = 0;
  for (int st = 0; st <= qtB; ++st) {
    const bf16* Kc = Ks + cur * KSZ;
    const bf16* Vc = VTs + cur * VSZ;

    if (st <= pid) {
      // ---- phase 1: full-tile step on own tile (A: qtA, B: qtB) ----
      const bool diag = (tl == 0) && (st == qtA);  // B never diag here (st<=pid<qtB)

      f32x4 sc[8] = {};
      __builtin_amdgcn_s_setprio(1);
#pragma unroll
      for (int ks = 0; ks < 2; ++ks)
#pragma unroll
        for (int j = 0; j < 8; ++j) {
          bf16x8 bk = ldsv8(Kc + (j * 16 + l16) * 72 + (ks * 4 + quad) * 8);
          sc[j] = __builtin_amdgcn_mfma_f32_16x16x32_bf16(aq[ks], bk, sc[j], 0, 0, 0);
        }
      __builtin_amdgcn_s_setprio(0);

#pragma unroll
      for (int r = 0; r < 4; ++r) {
        const int rloc = wrow + quad * 4 + r;
        bf16* prow = Pw + (quad * 4 + r) * 136;
        const int psw = quad << 3;
#pragma unroll
        for (int j = 0; j < 8; ++j) {
          float v = sc[j][r];
          if (diag && (j * 16 + l16) > rloc) v = -1e30f;  // exp2 -> 0
          prow[(j * 16 + l16) ^ psw] = __float2bfloat16(__builtin_amdgcn_exp2f(v));
        }
      }

      __builtin_amdgcn_s_setprio(1);
#pragma unroll
      for (int ks = 0; ks < 4; ++ks) {
        bf16x8 ap = ldsv8(Pw + l16 * 136 + (((ks * 4 + quad) ^ (l16 >> 2)) << 3));
        lacc = __builtin_amdgcn_mfma_f32_16x16x32_bf16(ap, vones, lacc, 0, 0, 0);
#pragma unroll
        for (int j = 0; j < 4; ++j) {
          int d = j * 16 + l16;
          bf16x8 bv = ldsv8(Vc + d * 136 + (((ks * 4 + quad) ^ (2 * j + (l16 >> 3))) << 3));
          o[j] = __builtin_amdgcn_mfma_f32_16x16x32_bf16(ap, bv, o[j], 0, 0, 0);
        }
      }
      __builtin_amdgcn_s_setprio(0);

      // ---- transition at the end of phase 1 (A-waves only) ----
      if (st == pid && tl == 0) {
        // tile A complete: write output
#pragma unroll
        for (int r = 0; r < 4; ++r) {
          int tt = qtA * 128 + wrow + quad * 4 + r;
          float inv = 1.f / lacc[r];
#pragma unroll
          for (int j = 0; j < 4; ++j)
            Yh[(size_t)tt * 1024 + j * 16 + l16] = __float2bfloat16(o[j][r] * inv);
        }
        // switch to tile B partner rows
        int sg = qtB * 128 + wrow + l16;
        const bf16* qp = xproj + rowbase + (size_t)(sg >> 4) * 3072 + ((sg & 15) << 6);
#pragma unroll
        for (int ks = 0; ks < 2; ++ks)
          aq[ks] = *(const bf16x8*)(qp + ks * 32 + quad * 8);
#pragma unroll
        for (int j = 0; j < 4; ++j) o[j] = (f32x4){0.f, 0.f, 0.f, 0.f};
        lacc = (f32x4){0.f, 0.f, 0.f, 0.f};
      }
    } else {
      // ---- phase 2: all waves on tile B, key half kh = tl ----
      const int kh = tl;
      const bool diag = (st == qtB);

      f32x4 sc[4] = {};
      __builtin_amdgcn_s_setprio(1);
#pragma unroll
      for (int ks = 0; ks < 2; ++ks)
#pragma unroll
        for (int j = 0; j < 4; ++j) {
          bf16x8 bk = ldsv8(Kc + (kh * 64 + j * 16 + l16) * 72 + (ks * 4 + quad) * 8);
          sc[j] = __builtin_amdgcn_mfma_f32_16x16x32_bf16(aq[ks], bk, sc[j], 0, 0, 0);
        }
      __builtin_amdgcn_s_setprio(0);

#pragma unroll
      for (int r = 0; r < 4; ++r) {
        const int rloc = wrow + quad * 4 + r;
        bf16* prow = Pw + (quad * 4 + r) * 136;
        const int psw = quad << 3;
#pragma unroll
        for (int j = 0; j < 4; ++j) {
          float v = sc[j][r];
          const int key = kh * 64 + j * 16 + l16;
          if (diag && key > rloc) v = -1e30f;  // exp2 -> 0
          prow[key ^ psw] = __float2bfloat16(__builtin_amdgcn_exp2f(v));
        }
      }

      __builtin_amdgcn_s_setprio(1);
#pragma unroll
      for (int c = 0; c < 2; ++c) {
        const int ks = kh * 2 + c;  // key chunk within the tile
        bf16x8 ap = ldsv8(Pw + l16 * 136 + (((ks * 4 + quad) ^ (l16 >> 2)) << 3));
        lacc = __builtin_amdgcn_mfma_f32_16x16x32_bf16(ap, vones, lacc, 0, 0, 0);
#pragma unroll
        for (int j = 0; j < 4; ++j) {
          int d = j * 16 + l16;
          bf16x8 bv = ldsv8(Vc + d * 136 + (((ks * 4 + quad) ^ (2 * j + (l16 >> 3))) << 3));
          o[j] = __builtin_amdgcn_mfma_f32_16x16x32_bf16(ap, bv, o[j], 0, 0, 0);
        }
      }
      __builtin_amdgcn_s_setprio(0);
    }

    // stage next tile into the other buffer; single barrier per step
    if (st < qtB) {
      WRITE_TILE(cur ^ 1);                      // tile st+1 (regs in flight)
      if (st + 2 <= qtB) ISSUE_LOADS(st + 2);   // hide under next compute
      __syncthreads();
      cur ^= 1;
    }
  }
#undef ISSUE_LOADS
#undef WRITE_TILE

  // ---- merge A's tile-B key-half partials into B, then tile-B epilogue ----
  __syncthreads();  // all compute done; Ks/VTs free for scratch
  {
    float* so = (float*)Ks;   // [8 waves][64 lanes][16] o partials (32 KB)
    float* sl = (float*)VTs;  // [8 waves][64 lanes][4]  lacc partials (8 KB)
    const int w8 = wave & 7;
    if (tl == 0) {
#pragma unroll
      for (int j = 0; j < 4; ++j)
        *(f32x4*)(so + ((w8 * 64 + lane) * 16) + j * 4) = o[j];
      *(f32x4*)(sl + (w8 * 64 + lane) * 4) = lacc;
    }
    __syncthreads();
    if (tl == 1) {
#pragma unroll
      for (int j = 0; j < 4; ++j)
        o[j] += *(const f32x4*)(so + ((w8 * 64 + lane) * 16) + j * 4);
      lacc += *(const f32x4*)(sl + (w8 * 64 + lane) * 4);
#pragma unroll
      for (int r = 0; r < 4; ++r) {
        int tt = qtB * 128 + wrow + quad * 4 + r;
        float inv = 1.f / lacc[r];
#pragma unroll
        for (int j = 0; j < 4; ++j)
          Yh[(size_t)tt * 1024 + j * 16 + l16] = __float2bfloat16(o[j][r] * inv);
      }
    }
  }
}

extern "C" void kernel_launch(void* const* d_in, const int* in_sizes, int n_in,
                              void* d_out, int out_size, void* d_ws, size_t ws_size,
                              hipStream_t stream) {
  (void)out_size;
  const void* px     = d_in[0];
  const void* pWqkv  = (n_in > 1) ? d_in[1] : d_in[0];
  const void* pbqkv  = (n_in > 2) ? d_in[2] : d_in[0];
  const void* pWproj = (n_in > 3) ? d_in[3] : d_in[0];
  const void* pbproj = (n_in > 4) ? d_in[4] : d_in[0];
  for (int i = 0; i < n_in; ++i) {
    switch (in_sizes[i]) {
      case 4194304: px     = d_in[i]; break;
      case 3145728: pWqkv  = d_in[i]; break;
      case 3072:    pbqkv  = d_in[i]; break;
      case 1048576: pWproj = d_in[i]; break;
      case 1024:    pbproj = d_in[i]; break;
      default: break;
    }
  }

  char* ws = (char*)d_ws;
  bf16* xproj = (bf16*)(ws + 0);  // [4096][3072] bf16, 25165824 B

  if (ws_size >= 41943040) {
    // Fused-prep layout (40 MB peak):
    //   xproj  [0,        25165824)             live k1..k3
    //   xb     [25165824, 33554432)             live k0..k1
    //   WqkvT  [33554432, 39845888)             live k0..k1
    //   WprojT [39845888, 41943040)             live k0..k4 (own slot)
    //   Yb     [27262976, 35651584) (over dead xb/WqkvT) live k3..k4
    bf16* xb     = (bf16*)(ws + 25165824);
    bf16* WqkvT  = (bf16*)(ws + 33554432);
    bf16* WprojT = (bf16*)(ws + 39845888);
    bf16* Yb     = (bf16*)(ws + 27262976);

    prep_k<<<dim3(6144), 256, 0, stream>>>((const float*)px, xb, pWqkv, WqkvT,
                                           pWproj, WprojT);                     // k0
    gemm128<0, 128><<<dim3(32, 24), 256, 0, stream>>>(xb, WqkvT, pbqkv, xproj); // k1
    attn_k<<<dim3(8, 32), 1024, 0, stream>>>(xproj, Yb);                        // k3
    gemm128<1, 64><<<dim3(32, 16), 256, 0, stream>>>(Yb, WprojT, pbproj, d_out);// k4
  } else if (ws_size >= 39845888) {
    // R2 big-ws layout, separate prep kernels.
    bf16* xb     = (bf16*)(ws + 25165824);
    bf16* WqkvT  = (bf16*)(ws + 33554432);
    bf16* WprojT = (bf16*)(ws + 25165824);
    bf16* Yb     = (bf16*)(ws + 27262976);

    cvt_k<<<dim3(2048), 256, 0, stream>>>((const float*)px, xb);
    cvtT_k<<<dim3(96, 32), 256, 0, stream>>>(pWqkv, WqkvT, 1024, 3072);
    gemm128<0, 128><<<dim3(32, 24), 256, 0, stream>>>(xb, WqkvT, pbqkv, xproj);
    cvtT_k<<<dim3(32, 32), 256, 0, stream>>>(pWproj, WprojT, 1024, 1024);
    attn_k<<<dim3(8, 32), 1024, 0, stream>>>(xproj, Yb);
    gemm128<1, 64><<<dim3(32, 16), 256, 0, stream>>>(Yb, WprojT, pbproj, d_out);
  } else {
    // Proven 35.65 MB fallback, fp32 A path in the QKV GEMM.
    bf16* WqkvT  = (bf16*)(ws + 25165824);
    bf16* WprojT = (bf16*)(ws + 25165824);
    bf16* Yb     = (bf16*)(ws + 27262976);

    cvtT_k<<<dim3(96, 32), 256, 0, stream>>>(pWqkv, WqkvT, 1024, 3072);
    gemm128<0, 128><<<dim3(32, 24), 256, 0, stream>>>(px, WqkvT, pbqkv, xproj);
    cvtT_k<<<dim3(32, 32), 256, 0, stream>>>(pWproj, WprojT, 1024, 1024);
    attn_k<<<dim3(8, 32), 1024, 0, stream>>>(xproj, Yb);
    gemm128<1, 64><<<dim3(32, 16), 256, 0, stream>>>(Yb, WprojT, pbproj, d_out);
  }
}

// Round 18
// 185.887 us; speedup vs baseline: 1.0776x; 1.0776x over previous
//
#include <hip/hip_runtime.h>
#include <hip/hip_bf16.h>
#include <stdint.h>

typedef __hip_bfloat16 bf16;
typedef __attribute__((ext_vector_type(8))) short bf16x8;  // MFMA A/B frag (4 VGPRs)
typedef __attribute__((ext_vector_type(4))) float f32x4;   // MFMA C/D frag

__device__ __forceinline__ bf16x8 ldsv8(const bf16* p) { return *(const bf16x8*)p; }

__device__ __forceinline__ short bf_bits(float f) {
  union { bf16 h; short s; } u; u.h = __float2bfloat16(f); return u.s;
}

// Q pre-scale: 1/sqrt(64) * log2(e), so attn can use exp2 (v_exp_f32) directly.
#define QSCALE 0.18033688011112042f

// async global->LDS, 16 B/lane. LDS dst must be wave-uniform base + lane*16,
// which our slot layout satisfies (slot = i*256 + wave*64 + lane).
#define ASYNC16(ldsdst, gsrc)                                                  \
  __builtin_amdgcn_global_load_lds(                                            \
      (const __attribute__((address_space(1))) void*)(gsrc),                   \
      (__attribute__((address_space(3))) void*)(ldsdst), 16, 0, 0)

// Runtime dtype sniff: true if buffer holds bf16 (vs fp32).
__device__ __forceinline__ bool is_bf16(const void* p) {
  const uint32_t* w = (const uint32_t*)p;
  int cnt = 0;
#pragma unroll 8
  for (int i = 0; i < 64; ++i) {
    uint32_t e = (w[i] >> 7) & 0xffu;
    cnt += (e >= 100u && e <= 150u) ? 1 : 0;
  }
  return cnt >= 40;
}

__device__ __forceinline__ float load_f32(const void* p, size_t idx, bool b16) {
  return b16 ? __bfloat162float(((const bf16*)p)[idx]) : ((const float*)p)[idx];
}

// ---------------- shared transpose-convert body ----------------
__device__ __forceinline__ void cvtT_body(const void* in, bf16* out, int R,
                                          int Ccols, int bx, int by,
                                          bf16 (*tile)[33]) {
  const bool b16 = is_bf16(in);
  int tx = threadIdx.x & 31, ty = threadIdx.x >> 5;
  int c0 = bx * 32, r0 = by * 32;
#pragma unroll
  for (int i = 0; i < 32; i += 8)
    tile[ty + i][tx] = __float2bfloat16(load_f32(in, (size_t)(r0 + ty + i) * Ccols + c0 + tx, b16));
  __syncthreads();
#pragma unroll
  for (int i = 0; i < 32; i += 8)
    out[(size_t)(c0 + ty + i) * R + r0 + tx] = tile[tx][ty + i];
}

// ---------------- fused prep: x cvt + WqkvT + WprojT in ONE launch ----------
// blocks [0,2048): x fp32->bf16 (8 elem/thread)
// blocks [2048,5120): Wqkv transpose-convert (96x32 tiles)
// blocks [5120,6144): Wproj transpose-convert (32x32 tiles)
// Branch is uniform per block (blockIdx.x), so cvtT_body's __syncthreads is safe.
__global__ __launch_bounds__(256) void prep_k(const float* __restrict__ x,
                                              bf16* __restrict__ xb,
                                              const void* __restrict__ Wqkv,
                                              bf16* __restrict__ WqkvT,
                                              const void* __restrict__ Wproj,
                                              bf16* __restrict__ WprojT) {
  __shared__ __align__(16) bf16 tile[32][33];
  const int id = blockIdx.x;
  if (id < 2048) {
    size_t i = (size_t)id * 256 + threadIdx.x;
    const float4 f0 = ((const float4*)x)[i * 2];
    const float4 f1 = ((const float4*)x)[i * 2 + 1];
    bf16x8 pk = {bf_bits(f0.x), bf_bits(f0.y), bf_bits(f0.z), bf_bits(f0.w),
                 bf_bits(f1.x), bf_bits(f1.y), bf_bits(f1.z), bf_bits(f1.w)};
    ((bf16x8*)xb)[i] = pk;
  } else if (id < 5120) {
    int id2 = id - 2048;
    cvtT_body(Wqkv, WqkvT, 1024, 3072, id2 % 96, id2 / 96, tile);
  } else {
    int id3 = id - 5120;
    cvtT_body(Wproj, WprojT, 1024, 1024, id3 % 32, id3 / 32, tile);
  }
}

// standalone cvtT (fallback paths)
__global__ __launch_bounds__(256) void cvtT_k(const void* __restrict__ in,
                                              bf16* __restrict__ out,
                                              int R, int Ccols) {
  __shared__ __align__(16) bf16 tile[32][33];
  cvtT_body(in, out, R, Ccols, blockIdx.x, blockIdx.y, tile);
}

// standalone cvt (fallback path)
__global__ __launch_bounds__(256) void cvt_k(const float* __restrict__ in,
                                             bf16* __restrict__ out) {
  size_t i = (size_t)blockIdx.x * 256 + threadIdx.x;
  const float4 f0 = ((const float4*)in)[i * 2];
  const float4 f1 = ((const float4*)in)[i * 2 + 1];
  bf16x8 pk = {bf_bits(f0.x), bf_bits(f0.y), bf_bits(f0.z), bf_bits(f0.w),
               bf_bits(f1.x), bf_bits(f1.y), bf_bits(f1.z), bf_bits(f1.w)};
  ((bf16x8*)out)[i] = pk;
}

// ---------------- 128xBN MFMA GEMM, A[M,1024] x BT[N,1024] ----------------
// m97-style global_load_lds staging (width 16). MODE 0: out = bf16 xproj
// [M][3072], Q cols x QSCALE (1/8 * log2e, see attn exp2). MODE 1: out =
// FLOAT32 [M][1024] (final output).
// T1 XCD swizzle, A-RESIDENT orientation (R16 best): each XCD's contiguous
// chunk spans FEW m-panels x ALL n-tiles -> A-panels stay L2-resident.
// Bijective: m = swz/gridDim.y, n = swz%gridDim.y.
template <int MODE, int BN>
__global__ __launch_bounds__(256) void gemm128(
    const void* __restrict__ Araw, const bf16* __restrict__ BT,
    const void* __restrict__ biasraw, void* __restrict__ outv) {
  constexpr int K = 1024;
  constexpr int NBF = BN / 32;  // B frags per wave (wave n-extent BN/2)
  __shared__ __align__(16) bf16 As[128 * 32];
  __shared__ __align__(16) bf16 Bs[BN * 32];
  const int tid = threadIdx.x;
  const int wave = tid >> 6, lane = tid & 63;
  const int quad = lane >> 4, l16 = lane & 15;
  // XCD-aware swizzle (gridDim.x = m-tiles, gridDim.y = n-tiles)
  const int nwg = gridDim.x * gridDim.y;
  const int lin = blockIdx.y * gridDim.x + blockIdx.x;
  const int swz = (lin & 7) * (nwg >> 3) + (lin >> 3);
  const int m0 = (swz / gridDim.y) * 128, n0 = (swz % gridDim.y) * BN;
  const int wm = (wave & 1) * 64, wn = (wave >> 1) * (BN / 2);
  const bool a16 = (MODE == 0) ? is_bf16(Araw) : true;
  const bool bias16 = is_bf16(biasraw);

  f32x4 acc[4][NBF] = {};

  for (int kt = 0; kt < K; kt += 32) {
    __syncthreads();
    if (MODE != 0 || a16) {
#pragma unroll
      for (int i = 0; i < 2; ++i) {  // A: 512 slots
        int slot = i * 256 + tid;
        int row = slot >> 2, col = (slot & 3) << 3;
        ASYNC16(As + slot * 8, ((const bf16*)Araw) + (size_t)(m0 + row) * K + kt + col);
      }
#pragma unroll
      for (int i = 0; i < BN / 64; ++i) {  // B: BN*4 slots
        int slot = i * 256 + tid;
        int row = slot >> 2, col = (slot & 3) << 3;
        ASYNC16(Bs + slot * 8, BT + (size_t)(n0 + row) * K + kt + col);
      }
    } else {  // fp32 A fallback: convert through registers
#pragma unroll
      for (int i = 0; i < 2; ++i) {
        int slot = i * 256 + tid;
        int row = slot >> 2, col = (slot & 3) << 3;
        const float* ap = ((const float*)Araw) + (size_t)(m0 + row) * K + kt + col;
        float4 f0 = *(const float4*)ap;
        float4 f1 = *(const float4*)(ap + 4);
        bf16x8 pk = {bf_bits(f0.x), bf_bits(f0.y), bf_bits(f0.z), bf_bits(f0.w),
                     bf_bits(f1.x), bf_bits(f1.y), bf_bits(f1.z), bf_bits(f1.w)};
        *(bf16x8*)(As + slot * 8) = pk;
        if (i * 256 < BN * 4)
          *(bf16x8*)(Bs + slot * 8) = *(const bf16x8*)(BT + (size_t)(n0 + row) * K + kt + col);
      }
    }
    __syncthreads();
    bf16x8 af[4], bfr[NBF];
#pragma unroll
    for (int i = 0; i < 4; ++i)
      af[i] = ldsv8(As + (wm + i * 16 + l16) * 32 + quad * 8);
#pragma unroll
    for (int j = 0; j < NBF; ++j)
      bfr[j] = ldsv8(Bs + (wn + j * 16 + l16) * 32 + quad * 8);
#pragma unroll
    for (int i = 0; i < 4; ++i)
#pragma unroll
      for (int j = 0; j < NBF; ++j)
        acc[i][j] = __builtin_amdgcn_mfma_f32_16x16x32_bf16(af[i], bfr[j], acc[i][j], 0, 0, 0);
  }

  float biasf[NBF];
#pragma unroll
  for (int j = 0; j < NBF; ++j)
    biasf[j] = load_f32(biasraw, n0 + wn + j * 16 + l16, bias16);

#pragma unroll
  for (int i = 0; i < 4; ++i)
#pragma unroll
    for (int j = 0; j < NBF; ++j) {
      int ng = n0 + wn + j * 16 + l16;
#pragma unroll
      for (int r = 0; r < 4; ++r) {
        int mg = m0 + wm + i * 16 + quad * 4 + r;  // C/D: row=quad*4+reg, col=l16
        float v = acc[i][j][r] + biasf[j];
        if (MODE == 1) {
          ((float*)outv)[(size_t)mg * 1024 + ng] = v;  // final output fp32
        } else {
          ((bf16*)outv)[(size_t)mg * 3072 + ng] =
              __float2bfloat16(ng < 1024 ? v * QSCALE : v);
        }
      }
    }
}

// ---------------- MFMA flash causal attention, 16-WAVE blocks ----------------
// EXACT R13/R16 kernel (verified best: attn 43.4 us steady, total 187.8).
// Static softmax via exp2 (Q carries QSCALE), denominator via all-ones MFMA,
// dbuf K/V LDS with single barrier/step. 1024 threads / 16 waves; waves 0-7
// own tile A (qt=pid) rows, waves 8-15 own tile B (qt=15-pid) -> 4 waves/SIMD.
// FOUR alternative structures measured WORSE via the same mechanism (extra
// live state -> scratch spills or ILP collapse at the 64-VGPR allocation):
// R10 merged-QK, R12 KV-split dual-stream, R14 KVBLK=64 diet, R17 key-half
// split (WRITE_SIZE 11->30 MB spill sentinel). This structure is the fixpoint.
// K/V staging shared by all 16 waves (1024 threads x 1 slot).
// Quirky reshape: head-row (h,s) of Q/K/V = 64 contiguous elems of xproj at
// row h*128+(s>>4), col (s&15)*64 (+1024 K, +2048 V). Q carries QSCALE.
// LDS 141.3 KB (fits 160; 1 block/CU). LDS swizzles:
//   V: element (d,s) at VT[d*136 + (s ^ ((d>>3)<<3))]
//   P: element (row,s) at Pw[row*136 + (s ^ ((row>>2)<<3))]
__global__ __launch_bounds__(1024, 4) void attn_k(const bf16* __restrict__ xproj,
                                                  bf16* __restrict__ Yb) {
  constexpr int KSZ = 128 * 72;   // elems per K buffer
  constexpr int VSZ = 64 * 136;   // elems per V buffer
  __shared__ __align__(16) bf16 Ks[2 * KSZ];        // [buf][s][d], stride 72
  __shared__ __align__(16) bf16 VTs[2 * VSZ];       // [buf][d][s^], swizzled
  __shared__ __align__(16) bf16 Ps[16 * 16 * 136];  // per-wave P round-trip

  const int tid = threadIdx.x;
  const int wave = tid >> 6, lane = tid & 63;
  const int quad = lane >> 4, l16 = lane & 15;
  const int tl = wave >> 3;                // 0: tile A, 1: tile B
  const int wrow = (wave & 7) * 16;        // row block within the tile
  const int pid = blockIdx.x;              // 0..7
  const int qtA = pid, qtB = 15 - pid;     // paired q-tiles, 17 tile-steps total
  const int qt = tl ? qtB : qtA;           // this wave's q-tile
  const int bh = blockIdx.y, b = bh >> 4, h = bh & 15;
  const size_t rowbase = (size_t)(b * 2048 + h * 128) * 3072;
  const int q0 = qt * 128;

  // all-ones bf16 B-fragment for the denominator MFMA (1.0bf16 = 0x3F80)
  const short onebits = (short)0x3F80;
  const bf16x8 vones = {onebits, onebits, onebits, onebits,
                        onebits, onebits, onebits, onebits};

  bf16x8 aq[2];  // Q frags persist (A-layout: m=l16, k=quad*8+j)
  {
    int sg = q0 + wrow + l16;
    const bf16* qp = xproj + rowbase + (size_t)(sg >> 4) * 3072 + ((sg & 15) << 6);
#pragma unroll
    for (int ks = 0; ks < 2; ++ks)
      aq[ks] = *(const bf16x8*)(qp + ks * 32 + quad * 8);
  }

  f32x4 o[4] = {};
  f32x4 lacc = {};  // softmax denominator accumulator (same layout as o)

  bf16* Pw = Ps + wave * (16 * 136);

  // per-thread staging slot (fixed for the whole kernel): 1024 slots
  const int sA = tid >> 3, blkA = tid & 7;

  bf16x8 kreg, vreg;
#define ISSUE_LOADS(stv)                                                        \
  {                                                                             \
    int sg0 = (stv)*128 + sA;                                                   \
    const bf16* b0 = xproj + rowbase + (size_t)(sg0 >> 4) * 3072 + ((sg0 & 15) << 6); \
    kreg = *(const bf16x8*)(b0 + 1024 + blkA * 8);                              \
    vreg = *(const bf16x8*)(b0 + 2048 + blkA * 8);                              \
  }
#define WRITE_TILE(buf)                                                         \
  {                                                                             \
    bf16* Kd = Ks + (buf)*KSZ;                                                  \
    bf16* Vd = VTs + (buf)*VSZ;                                                 \
    *(bf16x8*)(Kd + sA * 72 + blkA * 8) = kreg;                                 \
    const bf16* vv = (const bf16*)&vreg;                                        \
    const int ssw = sA ^ (blkA << 3);                                           \
    _Pragma("unroll")                                                           \
    for (int j = 0; j < 8; ++j) Vd[(blkA * 8 + j) * 136 + ssw] = vv[j];         \
  }

  // prologue: stage tile 0 into buf0, issue tile 1 (qtB >= 8 always)
  ISSUE_LOADS(0);
  WRITE_TILE(0);
  ISSUE_LOADS(1);
  __syncthreads();

  int cur = 0;
  for (int st = 0; st <= qtB; ++st) {
    const bf16* Kc = Ks + cur * KSZ;
    const bf16* Vc = VTs + cur * VSZ;

    if (st <= qt) {  // this wave's tile still has work at this step
      const bool diag = (st == qt);

      f32x4 sc[8] = {};
      __builtin_amdgcn_s_setprio(1);
#pragma unroll
      for (int ks = 0; ks < 2; ++ks)
#pragma unroll
        for (int j = 0; j < 8; ++j) {
          bf16x8 bk = ldsv8(Kc + (j * 16 + l16) * 72 + (ks * 4 + quad) * 8);
          sc[j] = __builtin_amdgcn_mfma_f32_16x16x32_bf16(aq[ks], bk, sc[j], 0, 0, 0);
        }
      __builtin_amdgcn_s_setprio(0);

      // static softmax: P = exp2(masked score), no reduce, no rescale
#pragma unroll
      for (int r = 0; r < 4; ++r) {
        const int rloc = wrow + quad * 4 + r;  // tile-local q-row
        bf16* prow = Pw + (quad * 4 + r) * 136;
        const int psw = quad << 3;  // row>>2 == quad
#pragma unroll
        for (int j = 0; j < 8; ++j) {
          float v = sc[j][r];
          if (diag && (j * 16 + l16) > rloc) v = -1e30f;  // exp2 -> 0
          prow[(j * 16 + l16) ^ psw] = __float2bfloat16(__builtin_amdgcn_exp2f(v));
        }
      }

      __builtin_amdgcn_s_setprio(1);
#pragma unroll
      for (int ks = 0; ks < 4; ++ks) {
        bf16x8 ap = ldsv8(Pw + l16 * 136 + (((ks * 4 + quad) ^ (l16 >> 2)) << 3));
        lacc = __builtin_amdgcn_mfma_f32_16x16x32_bf16(ap, vones, lacc, 0, 0, 0);
#pragma unroll
        for (int j = 0; j < 4; ++j) {
          int d = j * 16 + l16;
          bf16x8 bv = ldsv8(Vc + d * 136 + (((ks * 4 + quad) ^ (2 * j + (l16 >> 3))) << 3));
          o[j] = __builtin_amdgcn_mfma_f32_16x16x32_bf16(ap, bv, o[j], 0, 0, 0);
        }
      }
      __builtin_amdgcn_s_setprio(0);
    }

    // stage next tile into the other buffer; single barrier per step.
    // ALL threads run this (shared K/V staging), including tile-A waves
    // whose compute is done.
    if (st < qtB) {
      WRITE_TILE(cur ^ 1);                      // tile st+1 (regs in flight)
      if (st + 2 <= qtB) ISSUE_LOADS(st + 2);   // hide under next compute
      __syncthreads();
      cur ^= 1;
    }
  }
#undef ISSUE_LOADS
#undef WRITE_TILE

  bf16* Yh = Yb + (size_t)b * 2097152 + h * 64;  // Y[b][t][h*64+d]
#pragma unroll
  for (int r = 0; r < 4; ++r) {
    int tt = q0 + wrow + quad * 4 + r;
    float inv = 1.f / lacc[r];
#pragma unroll
    for (int j = 0; j < 4; ++j)
      Yh[(size_t)tt * 1024 + j * 16 + l16] = __float2bfloat16(o[j][r] * inv);
  }
}

extern "C" void kernel_launch(void* const* d_in, const int* in_sizes, int n_in,
                              void* d_out, int out_size, void* d_ws, size_t ws_size,
                              hipStream_t stream) {
  (void)out_size;
  const void* px     = d_in[0];
  const void* pWqkv  = (n_in > 1) ? d_in[1] : d_in[0];
  const void* pbqkv  = (n_in > 2) ? d_in[2] : d_in[0];
  const void* pWproj = (n_in > 3) ? d_in[3] : d_in[0];
  const void* pbproj = (n_in > 4) ? d_in[4] : d_in[0];
  for (int i = 0; i < n_in; ++i) {
    switch (in_sizes[i]) {
      case 4194304: px     = d_in[i]; break;
      case 3145728: pWqkv  = d_in[i]; break;
      case 3072:    pbqkv  = d_in[i]; break;
      case 1048576: pWproj = d_in[i]; break;
      case 1024:    pbproj = d_in[i]; break;
      default: break;
    }
  }

  char* ws = (char*)d_ws;
  bf16* xproj = (bf16*)(ws + 0);  // [4096][3072] bf16, 25165824 B

  if (ws_size >= 41943040) {
    // Fused-prep layout (40 MB peak):
    //   xproj  [0,        25165824)             live k1..k3
    //   xb     [25165824, 33554432)             live k0..k1
    //   WqkvT  [33554432, 39845888)             live k0..k1
    //   WprojT [39845888, 41943040)             live k0..k4 (own slot)
    //   Yb     [27262976, 35651584) (over dead xb/WqkvT) live k3..k4
    bf16* xb     = (bf16*)(ws + 25165824);
    bf16* WqkvT  = (bf16*)(ws + 33554432);
    bf16* WprojT = (bf16*)(ws + 39845888);
    bf16* Yb     = (bf16*)(ws + 27262976);

    prep_k<<<dim3(6144), 256, 0, stream>>>((const float*)px, xb, pWqkv, WqkvT,
                                           pWproj, WprojT);                     // k0
    gemm128<0, 128><<<dim3(32, 24), 256, 0, stream>>>(xb, WqkvT, pbqkv, xproj); // k1
    attn_k<<<dim3(8, 32), 1024, 0, stream>>>(xproj, Yb);                        // k3
    gemm128<1, 64><<<dim3(32, 16), 256, 0, stream>>>(Yb, WprojT, pbproj, d_out);// k4
  } else if (ws_size >= 39845888) {
    // R2 big-ws layout, separate prep kernels.
    bf16* xb     = (bf16*)(ws + 25165824);
    bf16* WqkvT  = (bf16*)(ws + 33554432);
    bf16* WprojT = (bf16*)(ws + 25165824);
    bf16* Yb     = (bf16*)(ws + 27262976);

    cvt_k<<<dim3(2048), 256, 0, stream>>>((const float*)px, xb);
    cvtT_k<<<dim3(96, 32), 256, 0, stream>>>(pWqkv, WqkvT, 1024, 3072);
    gemm128<0, 128><<<dim3(32, 24), 256, 0, stream>>>(xb, WqkvT, pbqkv, xproj);
    cvtT_k<<<dim3(32, 32), 256, 0, stream>>>(pWproj, WprojT, 1024, 1024);
    attn_k<<<dim3(8, 32), 1024, 0, stream>>>(xproj, Yb);
    gemm128<1, 64><<<dim3(32, 16), 256, 0, stream>>>(Yb, WprojT, pbproj, d_out);
  } else {
    // Proven 35.65 MB fallback, fp32 A path in the QKV GEMM.
    bf16* WqkvT  = (bf16*)(ws + 25165824);
    bf16* WprojT = (bf16*)(ws + 25165824);
    bf16* Yb     = (bf16*)(ws + 27262976);

    cvtT_k<<<dim3(96, 32), 256, 0, stream>>>(pWqkv, WqkvT, 1024, 3072);
    gemm128<0, 128><<<dim3(32, 24), 256, 0, stream>>>(px, WqkvT, pbqkv, xproj);
    cvtT_k<<<dim3(32, 32), 256, 0, stream>>>(pWproj, WprojT, 1024, 1024);
    attn_k<<<dim3(8, 32), 1024, 0, stream>>>(xproj, Yb);
    gemm128<1, 64><<<dim3(32, 16), 256, 0, stream>>>(Yb, WprojT, pbproj, d_out);
  }
}